// Round 1
// 445.868 us; speedup vs baseline: 1.1205x; 1.1205x over previous
//
#include <hip/hip_runtime.h>
#include <hip/hip_bf16.h>
#include <stdint.h>

typedef __bf16 bf16_t;
typedef __bf16 bf16x8 __attribute__((ext_vector_type(8)));
typedef float f32x4 __attribute__((ext_vector_type(4)));

#define SEQ    4096
#define NROWS  16384   // B * N
#define DMODEL 1024
#define NH     16

// async 16B global->LDS DMA. LDS dest is wave-uniform base + lane*16 (m104).
__device__ __forceinline__ void async_cp16(const bf16_t* g, bf16_t* l) {
  __builtin_amdgcn_global_load_lds((const __attribute__((address_space(1))) void*)g,
                                   (__attribute__((address_space(3))) void*)l,
                                   16, 0, 0);
}

#define BARRIER() asm volatile("s_barrier" ::: "memory")
#define WAITVM(N) asm volatile("s_waitcnt vmcnt(" #N ")" ::: "memory")

// ---------------- fp32 -> bf16 convert (8 elems/thread) ----------------
__global__ __launch_bounds__(256) void f2b_kernel(const float* __restrict__ x,
                                                  bf16_t* __restrict__ y, int n8) {
  int i = blockIdx.x * 256 + threadIdx.x;
  if (i >= n8) return;
  const float4* xp = (const float4*)x + (size_t)i * 2;
  float4 a = xp[0], b = xp[1];
  bf16x8 o;
  o[0] = (bf16_t)a.x; o[1] = (bf16_t)a.y; o[2] = (bf16_t)a.z; o[3] = (bf16_t)a.w;
  o[4] = (bf16_t)b.x; o[5] = (bf16_t)b.y; o[6] = (bf16_t)b.z; o[7] = (bf16_t)b.w;
  *((bf16x8*)y + i) = o;
}

// 4 weight conversions + kv zero in one dispatch (blockIdx.y selects job)
__global__ __launch_bounds__(256) void f2b4_kernel(const float* __restrict__ x0, bf16_t* __restrict__ y0,
                                                   const float* __restrict__ x1, bf16_t* __restrict__ y1,
                                                   const float* __restrict__ x2, bf16_t* __restrict__ y2,
                                                   const float* __restrict__ x3, bf16_t* __restrict__ y3,
                                                   float* __restrict__ kvz, int kvn4, int n8) {
  int i = blockIdx.x * 256 + threadIdx.x;
  if (blockIdx.y == 4) {
    if (i < kvn4) ((float4*)kvz)[i] = make_float4(0.f, 0.f, 0.f, 0.f);
    return;
  }
  if (i >= n8) return;
  const float* x = (blockIdx.y == 0) ? x0 : (blockIdx.y == 1) ? x1 : (blockIdx.y == 2) ? x2 : x3;
  bf16_t* y = (blockIdx.y == 0) ? y0 : (blockIdx.y == 1) ? y1 : (blockIdx.y == 2) ? y2 : y3;
  const float4* xp = (const float4*)x + (size_t)i * 2;
  float4 a = xp[0], b = xp[1];
  bf16x8 o;
  o[0] = (bf16_t)a.x; o[1] = (bf16_t)a.y; o[2] = (bf16_t)a.z; o[3] = (bf16_t)a.w;
  o[4] = (bf16_t)b.x; o[5] = (bf16_t)b.y; o[6] = (bf16_t)b.z; o[7] = (bf16_t)b.w;
  *((bf16x8*)y + i) = o;
}

// ---------------- 256x256 8-phase GEMM (T2+T3+T4+T5) ----------------
// C[m,n] = sum_k A[m,k]*Bt[n,k] + bias[n].  M=16384, N=1024, K=1024 fixed.
// 512 threads = 8 waves (2M x 4N), per-wave out 128x64 (acc[8][4]).
// LDS: 2 K-tile buffers x (A[256][64] + B[256][64]) bf16 = 128 KiB.
// Staging granularity: half-tile (128 rows x 64 k = 16 KB = 2 gload_lds/thread).
// Raw s_barrier + counted vmcnt (8/6 per wait point); never drains to 0 in main loop.

template <int QM, int QN>
__device__ __forceinline__ void mm16(f32x4 (&acc)[8][4], const bf16x8 (&af)[2][4],
                                     const bf16x8 (&bf)[2][2]) {
#pragma unroll
  for (int ks = 0; ks < 2; ++ks)
#pragma unroll
    for (int i = 0; i < 4; ++i)
#pragma unroll
      for (int j = 0; j < 2; ++j)
        acc[QM * 4 + i][QN * 2 + j] = __builtin_amdgcn_mfma_f32_16x16x32_bf16(
            af[ks][i], bf[ks][j], acc[QM * 4 + i][QN * 2 + j], 0, 0, 0);
}

__device__ __forceinline__ void lda4(bf16x8 (&af)[2][4], const bf16_t* buf, int row0,
                                     int quad, int swz) {
#pragma unroll
  for (int ks = 0; ks < 2; ++ks)
#pragma unroll
    for (int i = 0; i < 4; ++i)
      af[ks][i] = *(const bf16x8*)(buf + (row0 + i * 16) * 64 + (((ks * 4 + quad) ^ swz) * 8));
}

__device__ __forceinline__ void ldb2(bf16x8 (&bf)[2][2], const bf16_t* buf, int row0,
                                     int quad, int swz) {
#pragma unroll
  for (int ks = 0; ks < 2; ++ks)
#pragma unroll
    for (int j = 0; j < 2; ++j)
      bf[ks][j] = *(const bf16x8*)(buf + (row0 + j * 16) * 64 + (((ks * 4 + quad) ^ swz) * 8));
}

// gsrc already includes per-thread (row, swizzled col) offset; dest is wave-uniform.
__device__ __forceinline__ void stg(bf16_t* dst, const bf16_t* gsrc, int half, int kb,
                                    int wave8) {
  async_cp16(gsrc + (size_t)(half * 128) * 1024 + kb, dst + (half * 128 + wave8) * 64);
  async_cp16(gsrc + (size_t)(half * 128 + 64) * 1024 + kb, dst + (half * 128 + 64 + wave8) * 64);
}

// MODE 0: bf16 C    MODE 1: fp32 C
template <int MODE>
__global__ __launch_bounds__(512, 2) void gemm256(const bf16_t* __restrict__ A,
                                                  const bf16_t* __restrict__ Bt,
                                                  const float* __restrict__ bias,
                                                  void* __restrict__ Cout) {
  constexpr int K = 1024, N = 1024;
  __shared__ bf16_t sA0[256 * 64];
  __shared__ bf16_t sB0[256 * 64];
  __shared__ bf16_t sA1[256 * 64];
  __shared__ bf16_t sB1[256 * 64];

  const int tid = threadIdx.x;
  const int lane = tid & 63, wave = tid >> 6;
  const int lrow = lane & 15, quad = lane >> 4, swz = lrow & 7;
  const int wm = (wave >> 2) * 64;   // 0 / 64   (M offset inside each 128-half)
  const int wn = (wave & 3) * 32;    // 0..96    (N offset inside each 128-half)
  const int wave8 = wave * 8;

  // XCD-bijective decode: 8 consecutive by-bands per XCD; 4 bx blocks of a by on one XCD.
  const int id = blockIdx.x;                     // 0..255
  const int bx = (id >> 3) & 3;                  // N block
  const int by = ((id & 7) << 3) | (id >> 5);    // M block 0..63
  const int m0 = by * 256, n0 = bx * 256;

  // staging source: 64 rows x 8 colgroups per pass, swizzled col (T2, both-sides scheme)
  const int srow = tid >> 3;                          // 0..63
  const int scg = ((tid & 7) ^ (srow & 7)) * 8;       // swizzled k-group
  const bf16_t* gA = A + (size_t)(m0 + srow) * K + scg;
  const bf16_t* gB = Bt + (size_t)(n0 + srow) * K + scg;

  f32x4 acc[8][4];
#pragma unroll
  for (int i = 0; i < 8; ++i)
#pragma unroll
    for (int j = 0; j < 4; ++j) acc[i][j] = (f32x4){0.f, 0.f, 0.f, 0.f};

  // prologue: tile0 fully + tile1 h0 (order matters for FIFO vmcnt counting)
  stg(sA0, gA, 0, 0, wave8);
  stg(sB0, gB, 0, 0, wave8);
  stg(sA0, gA, 1, 0, wave8);
  stg(sB0, gB, 1, 0, wave8);
  stg(sA1, gA, 0, 64, wave8);
  stg(sB1, gB, 0, 64, wave8);
  WAITVM(8);   // A0h0,B0h0 landed; 4 half-tiles in flight
  BARRIER();

  bf16x8 af[2][4], bf0[2][2], bf1[2][2];

#pragma unroll 1
  for (int it = 0; it < 7; ++it) {   // tiles t=2it, t+1; NT=16, last pair peeled
    const int kb = it * 128;
    // P0: read A(t)h0 + B(t)h0; stage A(t+1)h1
    lda4(af, sA0, wm + lrow, quad, swz);
    ldb2(bf0, sB0, wn + lrow, quad, swz);
    stg(sA1, gA, 1, kb + 64, wave8);
    BARRIER();
    __builtin_amdgcn_s_setprio(1); mm16<0, 0>(acc, af, bf0); __builtin_amdgcn_s_setprio(0);
    WAITVM(6);
    BARRIER();
    // P1: read B(t)h1; stage B(t+1)h1
    ldb2(bf1, sB0, 128 + wn + lrow, quad, swz);
    stg(sB1, gB, 1, kb + 64, wave8);
    BARRIER();
    __builtin_amdgcn_s_setprio(1); mm16<0, 1>(acc, af, bf1); __builtin_amdgcn_s_setprio(0);
    BARRIER();
    // P2: read A(t)h1; stage A(t+2)h0
    lda4(af, sA0, 128 + wm + lrow, quad, swz);
    stg(sA0, gA, 0, kb + 128, wave8);
    BARRIER();
    __builtin_amdgcn_s_setprio(1); mm16<1, 0>(acc, af, bf0); __builtin_amdgcn_s_setprio(0);
    BARRIER();
    // P3: stage B(t+2)h0
    stg(sB0, gB, 0, kb + 128, wave8);
    BARRIER();
    __builtin_amdgcn_s_setprio(1); mm16<1, 1>(acc, af, bf1); __builtin_amdgcn_s_setprio(0);
    WAITVM(8);
    BARRIER();
    // P4: read A(t+1)h0 + B(t+1)h0; stage A(t+2)h1
    lda4(af, sA1, wm + lrow, quad, swz);
    ldb2(bf0, sB1, wn + lrow, quad, swz);
    stg(sA0, gA, 1, kb + 128, wave8);
    BARRIER();
    __builtin_amdgcn_s_setprio(1); mm16<0, 0>(acc, af, bf0); __builtin_amdgcn_s_setprio(0);
    WAITVM(6);
    BARRIER();
    // P5: read B(t+1)h1; stage B(t+2)h1
    ldb2(bf1, sB1, 128 + wn + lrow, quad, swz);
    stg(sB0, gB, 1, kb + 128, wave8);
    BARRIER();
    __builtin_amdgcn_s_setprio(1); mm16<0, 1>(acc, af, bf1); __builtin_amdgcn_s_setprio(0);
    BARRIER();
    // P6: read A(t+1)h1; stage A(t+3)h0
    lda4(af, sA1, 128 + wm + lrow, quad, swz);
    stg(sA1, gA, 0, kb + 192, wave8);
    BARRIER();
    __builtin_amdgcn_s_setprio(1); mm16<1, 0>(acc, af, bf0); __builtin_amdgcn_s_setprio(0);
    BARRIER();
    // P7: stage B(t+3)h0
    stg(sB1, gB, 0, kb + 192, wave8);
    BARRIER();
    __builtin_amdgcn_s_setprio(1); mm16<1, 1>(acc, af, bf1); __builtin_amdgcn_s_setprio(0);
    WAITVM(8);
    BARRIER();
  }

  // peeled final iteration: tiles 14 (kb=896) and 15; no t+2/t+3 stages -> tightened waits
  {
    const int kb = 896;
    // P0: stage A(15)h1
    lda4(af, sA0, wm + lrow, quad, swz);
    ldb2(bf0, sB0, wn + lrow, quad, swz);
    stg(sA1, gA, 1, kb + 64, wave8);
    BARRIER();
    __builtin_amdgcn_s_setprio(1); mm16<0, 0>(acc, af, bf0); __builtin_amdgcn_s_setprio(0);
    WAITVM(6);
    BARRIER();
    // P1: stage B(15)h1
    ldb2(bf1, sB0, 128 + wn + lrow, quad, swz);
    stg(sB1, gB, 1, kb + 64, wave8);
    BARRIER();
    __builtin_amdgcn_s_setprio(1); mm16<0, 1>(acc, af, bf1); __builtin_amdgcn_s_setprio(0);
    BARRIER();
    // P2
    lda4(af, sA0, 128 + wm + lrow, quad, swz);
    BARRIER();
    __builtin_amdgcn_s_setprio(1); mm16<1, 0>(acc, af, bf0); __builtin_amdgcn_s_setprio(0);
    BARRIER();
    // P3
    BARRIER();
    __builtin_amdgcn_s_setprio(1); mm16<1, 1>(acc, af, bf1); __builtin_amdgcn_s_setprio(0);
    WAITVM(4);
    BARRIER();
    // P4
    lda4(af, sA1, wm + lrow, quad, swz);
    ldb2(bf0, sB1, wn + lrow, quad, swz);
    BARRIER();
    __builtin_amdgcn_s_setprio(1); mm16<0, 0>(acc, af, bf0); __builtin_amdgcn_s_setprio(0);
    WAITVM(0);
    BARRIER();
    // P5
    ldb2(bf1, sB1, 128 + wn + lrow, quad, swz);
    BARRIER();
    __builtin_amdgcn_s_setprio(1); mm16<0, 1>(acc, af, bf1); __builtin_amdgcn_s_setprio(0);
    BARRIER();
    // P6
    lda4(af, sA1, 128 + wm + lrow, quad, swz);
    BARRIER();
    __builtin_amdgcn_s_setprio(1); mm16<1, 0>(acc, af, bf0); __builtin_amdgcn_s_setprio(0);
    BARRIER();
    // P7
    __builtin_amdgcn_s_setprio(1); mm16<1, 1>(acc, af, bf1); __builtin_amdgcn_s_setprio(0);
  }

  // epilogue
  float bv_[4];
#pragma unroll
  for (int nj = 0; nj < 4; ++nj)
    bv_[nj] = bias[n0 + (nj >> 1) * 128 + wn + (nj & 1) * 16 + lrow];

  if constexpr (MODE == 0) {
    bf16_t* C = (bf16_t*)Cout;
#pragma unroll
    for (int mi = 0; mi < 8; ++mi) {
      int row = m0 + (mi >> 2) * 128 + wm + (mi & 3) * 16 + quad * 4;
#pragma unroll
      for (int nj = 0; nj < 4; ++nj) {
        int col = n0 + (nj >> 1) * 128 + wn + (nj & 1) * 16 + lrow;
#pragma unroll
        for (int r = 0; r < 4; ++r)
          C[(size_t)(row + r) * N + col] = (bf16_t)(acc[mi][nj][r] + bv_[nj]);
      }
    }
  } else {
    float* C = (float*)Cout;
#pragma unroll
    for (int mi = 0; mi < 8; ++mi) {
      int row = m0 + (mi >> 2) * 128 + wm + (mi & 3) * 16 + quad * 4;
#pragma unroll
      for (int nj = 0; nj < 4; ++nj) {
        int col = n0 + (nj >> 1) * 128 + wn + (nj & 1) * 16 + lrow;
#pragma unroll
        for (int r = 0; r < 4; ++r)
          C[(size_t)(row + r) * N + col] = acc[mi][nj][r] + bv_[nj];
      }
    }
  }
}

// ---------------- kv accumulation via MFMA: kv[bh] += K_chunk^T * V_chunk ----------------
#define KVCH 512
__global__ __launch_bounds__(256) void kv_accum_mfma(const bf16_t* __restrict__ kp,
                                                     const bf16_t* __restrict__ vp,
                                                     float* __restrict__ kv) {
  __shared__ bf16_t sK[128][66];
  __shared__ bf16_t sV[128][66];
  int bx = blockIdx.x;
  int chunk = bx & 7;
  int bh = bx >> 3;
  int b = bh >> 4, h = bh & 15;
  int tid = threadIdx.x, lane = tid & 63, wave = tid >> 6;
  int lrow = lane & 15, quad = lane >> 4;

  f32x4 zero = {0.f, 0.f, 0.f, 0.f};
  f32x4 acc[4][4];
#pragma unroll
  for (int i = 0; i < 4; ++i)
#pragma unroll
    for (int j = 0; j < 4; ++j) acc[i][j] = zero;

  const int srow = tid >> 3;
  const int scol = (tid & 7) * 8;
  const size_t gbase0 = ((size_t)(b * SEQ + chunk * KVCH)) * DMODEL + h * 64 + scol;
  const int krow0 = wave * 32 + quad * 8;

  for (int s = 0; s < KVCH / 128; ++s) {
    bf16x8 kr[4], vr[4];
#pragma unroll
    for (int p = 0; p < 4; ++p) {
      size_t g = gbase0 + (size_t)(s * 128 + p * 32 + srow) * DMODEL;
      kr[p] = *(const bf16x8*)(kp + g);
      vr[p] = *(const bf16x8*)(vp + g);
    }
    __syncthreads();
#pragma unroll
    for (int p = 0; p < 4; ++p) {
      *(bf16x8*)&sK[p * 32 + srow][scol] = kr[p];
      *(bf16x8*)&sV[p * 32 + srow][scol] = vr[p];
    }
    __syncthreads();
    bf16x8 af[4], bfr[4];
#pragma unroll
    for (int i = 0; i < 4; ++i)
#pragma unroll
      for (int j = 0; j < 8; ++j) {
        af[i][j] = sK[krow0 + j][i * 16 + lrow];
        bfr[i][j] = sV[krow0 + j][i * 16 + lrow];
      }
#pragma unroll
    for (int i = 0; i < 4; ++i)
#pragma unroll
      for (int j = 0; j < 4; ++j)
        acc[i][j] = __builtin_amdgcn_mfma_f32_16x16x32_bf16(af[i], bfr[j], acc[i][j], 0, 0, 0);
  }

  float* dst = kv + (size_t)bh * 64 * 64;
#pragma unroll
  for (int i = 0; i < 4; ++i)
#pragma unroll
    for (int j = 0; j < 4; ++j)
#pragma unroll
      for (int r = 0; r < 4; ++r)
        atomicAdd(&dst[(i * 16 + quad * 4 + r) * 64 + j * 16 + lrow], acc[i][j][r]);
}

// ---------------- attention apply with fused kv-norm AND fused q-xnorm ----------------
// q is the raw Q projection (bias added), row-major [16384][1024] bf16.
// q-norm is a per-row scalar -> computed from the A-fragments and applied post-MFMA.
__global__ __launch_bounds__(256) void attn_gemm(const bf16_t* __restrict__ q,
                                                 const float* __restrict__ kv,
                                                 const float* __restrict__ gamma,
                                                 bf16_t* __restrict__ att) {
  __shared__ float sKV[64][65];
  __shared__ float sScale[64];
  int bx = blockIdx.x;          // bh*32 + chunk
  int chunk = bx & 31, bh = bx >> 5;
  int b = bh >> 4, h = bh & 15;
  int tid = threadIdx.x, lane = tid & 63, wave = tid >> 6;
  int lrow = lane & 15, quad = lane >> 4;
  int n0 = chunk * 128 + wave * 32;
  const float g = gamma[h];

  // stage kv (4096 floats) + row-norm partials
  {
    const float* src = kv + (size_t)bh * 64 * 64 + (tid >> 2) * 64 + (tid & 3) * 16;
    float4 v0 = *(const float4*)src;
    float4 v1 = *(const float4*)(src + 4);
    float4 v2 = *(const float4*)(src + 8);
    float4 v3 = *(const float4*)(src + 12);
    float* d = &sKV[tid >> 2][(tid & 3) * 16];
    *(float4*)d = v0; *(float4*)(d + 4) = v1; *(float4*)(d + 8) = v2; *(float4*)(d + 12) = v3;
    float ss = v0.x*v0.x + v0.y*v0.y + v0.z*v0.z + v0.w*v0.w
             + v1.x*v1.x + v1.y*v1.y + v1.z*v1.z + v1.w*v1.w
             + v2.x*v2.x + v2.y*v2.y + v2.z*v2.z + v2.w*v2.w
             + v3.x*v3.x + v3.y*v3.y + v3.z*v3.z + v3.w*v3.w;
    ss += __shfl_xor(ss, 1);
    ss += __shfl_xor(ss, 2);
    if ((tid & 3) == 0) sScale[tid >> 2] = g * rsqrtf(ss);
  }
  __syncthreads();

  const bf16_t* qbase = q + (size_t)b * SEQ * DMODEL + (size_t)h * 64;

  // load q frags for both ks
  bf16x8 af[2][2];
#pragma unroll
  for (int ks = 0; ks < 2; ++ks)
#pragma unroll
    for (int i = 0; i < 2; ++i)
      af[ks][i] = *(const bf16x8*)(qbase + (size_t)(n0 + i * 16 + lrow) * DMODEL + ks * 32 + quad * 8);

  // per-row q xnorm scale: ss over full 64 k; redistribute lrow->quad*4+r lanes
  float qsc[2][4];
#pragma unroll
  for (int i = 0; i < 2; ++i) {
    float ss = 0.f;
#pragma unroll
    for (int ks = 0; ks < 2; ++ks)
#pragma unroll
      for (int e = 0; e < 8; ++e) { float v = (float)af[ks][i][e]; ss += v * v; }
    ss += __shfl_xor(ss, 16);
    ss += __shfl_xor(ss, 32);
#pragma unroll
    for (int r = 0; r < 4; ++r)
      qsc[i][r] = g * rsqrtf(__shfl(ss, quad * 4 + r));
  }

  f32x4 zero = {0.f, 0.f, 0.f, 0.f};
  f32x4 acc[2][4];
#pragma unroll
  for (int i = 0; i < 2; ++i)
#pragma unroll
    for (int j = 0; j < 4; ++j) acc[i][j] = zero;

#pragma unroll
  for (int ks = 0; ks < 2; ++ks) {
    int k0 = ks * 32 + quad * 8;
    float sc[8];
#pragma unroll
    for (int j = 0; j < 8; ++j) sc[j] = sScale[k0 + j];
    bf16x8 bfr[4];
#pragma unroll
    for (int jt = 0; jt < 4; ++jt)
#pragma unroll
      for (int j = 0; j < 8; ++j)
        bfr[jt][j] = (bf16_t)(sKV[k0 + j][jt * 16 + lrow] * sc[j]);
#pragma unroll
    for (int i = 0; i < 2; ++i)
#pragma unroll
      for (int j = 0; j < 4; ++j)
        acc[i][j] = __builtin_amdgcn_mfma_f32_16x16x32_bf16(af[ks][i], bfr[j], acc[i][j], 0, 0, 0);
  }
#pragma unroll
  for (int i = 0; i < 2; ++i)
#pragma unroll
    for (int j = 0; j < 4; ++j)
#pragma unroll
      for (int r = 0; r < 4; ++r) {
        int n = n0 + i * 16 + quad * 4 + r;
        att[((size_t)(b * SEQ + n)) * DMODEL + h * 64 + j * 16 + lrow] =
            (bf16_t)(acc[i][j][r] * qsc[i][r]);
      }
}

// ---------------- launch ----------------
extern "C" void kernel_launch(void* const* d_in, const int* in_sizes, int n_in,
                              void* d_out, int out_size, void* d_ws, size_t ws_size,
                              hipStream_t stream) {
  const float* queries = (const float*)d_in[0];
  const float* keys    = (const float*)d_in[1];
  const float* values  = (const float*)d_in[2];
  const float* Wq = (const float*)d_in[3];
  const float* bq = (const float*)d_in[4];
  const float* Wk = (const float*)d_in[5];
  const float* bk = (const float*)d_in[6];
  const float* Wv = (const float*)d_in[7];
  const float* bv = (const float*)d_in[8];
  const float* Wo = (const float*)d_in[9];
  const float* bo = (const float*)d_in[10];
  const float* gamma = (const float*)d_in[11];

  char* ws = (char*)d_ws;
  size_t off = 0;
  auto alloc = [&](size_t bytes) -> void* {
    void* p = ws + off;
    off = (off + bytes + 255) & ~(size_t)255;
    return p;
  };
  const size_t actN = (size_t)NROWS * DMODEL;
  bf16_t* wqb  = (bf16_t*)alloc((size_t)DMODEL * DMODEL * 2);
  bf16_t* wkb  = (bf16_t*)alloc((size_t)DMODEL * DMODEL * 2);
  bf16_t* wvb  = (bf16_t*)alloc((size_t)DMODEL * DMODEL * 2);
  bf16_t* wob  = (bf16_t*)alloc((size_t)DMODEL * DMODEL * 2);
  bf16_t* actb = (bf16_t*)alloc(actN * 2);   // rotating bf16 A-operand buffer
  bf16_t* bufA = (bf16_t*)alloc(actN * 2);   // kproj, later qproj
  bf16_t* bufB = (bf16_t*)alloc(actN * 2);   // vproj, later att
  float*  kv   = (float*)alloc((size_t)64 * 64 * 64 * 4);

  int w8 = DMODEL * DMODEL / 8;
  int act8 = (int)(actN / 8);

  // weights + kv zero in one dispatch
  f2b4_kernel<<<dim3(w8 / 256, 5), 256, 0, stream>>>(Wk, wkb, Wv, wvb, Wq, wqb, Wo, wob,
                                                     kv, 64 * 64 * 64 / 4, w8);

  // K projection
  f2b_kernel<<<act8 / 256, 256, 0, stream>>>(keys, actb, act8);
  gemm256<0><<<256, 512, 0, stream>>>(actb, wkb, bk, bufA);
  // V projection
  f2b_kernel<<<act8 / 256, 256, 0, stream>>>(values, actb, act8);
  gemm256<0><<<256, 512, 0, stream>>>(actb, wvb, bv, bufB);

  // kv accumulation (MFMA)
  kv_accum_mfma<<<64 * 8, 256, 0, stream>>>(bufA, bufB, kv);

  // Q projection (plain; xnorm fused into attn_gemm) -> bufA (dead kproj)
  f2b_kernel<<<act8 / 256, 256, 0, stream>>>(queries, actb, act8);
  gemm256<0><<<256, 512, 0, stream>>>(actb, wqb, bq, bufA);

  // attention apply with fused kv-norm + q-norm -> att (into bufB, dead vproj)
  attn_gemm<<<64 * 32, 256, 0, stream>>>(bufA, kv, gamma, bufB);

  // output projection (fp32 out + bias)
  gemm256<1><<<256, 512, 0, stream>>>(bufB, wob, bo, d_out);
}

// Round 7
// 425.039 us; speedup vs baseline: 1.1754x; 1.0490x over previous
//
#include <hip/hip_runtime.h>
#include <hip/hip_bf16.h>
#include <stdint.h>

typedef __bf16 bf16_t;
typedef __bf16 bf16x8 __attribute__((ext_vector_type(8)));
typedef float f32x4 __attribute__((ext_vector_type(4)));

#define SEQ    4096
#define NROWS  16384   // B * N
#define DMODEL 1024
#define NH     16

// async 16B global->LDS DMA. LDS dest is wave-uniform base + lane*16 (m104).
__device__ __forceinline__ void async_cp16(const bf16_t* g, bf16_t* l) {
  __builtin_amdgcn_global_load_lds((const __attribute__((address_space(1))) void*)g,
                                   (__attribute__((address_space(3))) void*)l,
                                   16, 0, 0);
}

#define BARRIER() asm volatile("s_barrier" ::: "memory")
#define WAITVM(N) asm volatile("s_waitcnt vmcnt(" #N ")" ::: "memory")

// ---------------- fp32 -> bf16 convert (8 elems/thread) ----------------
__global__ __launch_bounds__(256) void f2b_kernel(const float* __restrict__ x,
                                                  bf16_t* __restrict__ y, int n8) {
  int i = blockIdx.x * 256 + threadIdx.x;
  if (i >= n8) return;
  const float4* xp = (const float4*)x + (size_t)i * 2;
  float4 a = xp[0], b = xp[1];
  bf16x8 o;
  o[0] = (bf16_t)a.x; o[1] = (bf16_t)a.y; o[2] = (bf16_t)a.z; o[3] = (bf16_t)a.w;
  o[4] = (bf16_t)b.x; o[5] = (bf16_t)b.y; o[6] = (bf16_t)b.z; o[7] = (bf16_t)b.w;
  *((bf16x8*)y + i) = o;
}

// 4 weight conversions in one dispatch (blockIdx.y selects job)
__global__ __launch_bounds__(256) void f2b4_kernel(const float* __restrict__ x0, bf16_t* __restrict__ y0,
                                                   const float* __restrict__ x1, bf16_t* __restrict__ y1,
                                                   const float* __restrict__ x2, bf16_t* __restrict__ y2,
                                                   const float* __restrict__ x3, bf16_t* __restrict__ y3,
                                                   int n8) {
  int i = blockIdx.x * 256 + threadIdx.x;
  if (i >= n8) return;
  const float* x = (blockIdx.y == 0) ? x0 : (blockIdx.y == 1) ? x1 : (blockIdx.y == 2) ? x2 : x3;
  bf16_t* y = (blockIdx.y == 0) ? y0 : (blockIdx.y == 1) ? y1 : (blockIdx.y == 2) ? y2 : y3;
  const float4* xp = (const float4*)x + (size_t)i * 2;
  float4 a = xp[0], b = xp[1];
  bf16x8 o;
  o[0] = (bf16_t)a.x; o[1] = (bf16_t)a.y; o[2] = (bf16_t)a.z; o[3] = (bf16_t)a.w;
  o[4] = (bf16_t)b.x; o[5] = (bf16_t)b.y; o[6] = (bf16_t)b.z; o[7] = (bf16_t)b.w;
  *((bf16x8*)y + i) = o;
}

// ---------------- 256x256 8-phase GEMM (T2+T3+T4+T5) ----------------
// C[m,n] = sum_k A[m,k]*Bt[n,k] + bias[n].  M=16384, N=1024, K=1024 fixed.
// 512 threads = 8 waves (2M x 4N), per-wave out 128x64 (acc[8][4]).
// LDS: 2 K-tile buffers x (A[256][64] + B[256][64]) bf16 = 128 KiB.
// Raw s_barrier + counted vmcnt (8/6 per wait point); never drains to 0 in main loop.

template <int QM, int QN>
__device__ __forceinline__ void mm16(f32x4 (&acc)[8][4], const bf16x8 (&af)[2][4],
                                     const bf16x8 (&bf)[2][2]) {
#pragma unroll
  for (int ks = 0; ks < 2; ++ks)
#pragma unroll
    for (int i = 0; i < 4; ++i)
#pragma unroll
      for (int j = 0; j < 2; ++j)
        acc[QM * 4 + i][QN * 2 + j] = __builtin_amdgcn_mfma_f32_16x16x32_bf16(
            af[ks][i], bf[ks][j], acc[QM * 4 + i][QN * 2 + j], 0, 0, 0);
}

__device__ __forceinline__ void lda4(bf16x8 (&af)[2][4], const bf16_t* buf, int row0,
                                     int quad, int swz) {
#pragma unroll
  for (int ks = 0; ks < 2; ++ks)
#pragma unroll
    for (int i = 0; i < 4; ++i)
      af[ks][i] = *(const bf16x8*)(buf + (row0 + i * 16) * 64 + (((ks * 4 + quad) ^ swz) * 8));
}

__device__ __forceinline__ void ldb2(bf16x8 (&bf)[2][2], const bf16_t* buf, int row0,
                                     int quad, int swz) {
#pragma unroll
  for (int ks = 0; ks < 2; ++ks)
#pragma unroll
    for (int j = 0; j < 2; ++j)
      bf[ks][j] = *(const bf16x8*)(buf + (row0 + j * 16) * 64 + (((ks * 4 + quad) ^ swz) * 8));
}

// gsrc already includes per-thread (row, swizzled col) offset; dest is wave-uniform.
__device__ __forceinline__ void stg(bf16_t* dst, const bf16_t* gsrc, int half, int kb,
                                    int wave8) {
  async_cp16(gsrc + (size_t)(half * 128) * 1024 + kb, dst + (half * 128 + wave8) * 64);
  async_cp16(gsrc + (size_t)(half * 128 + 64) * 1024 + kb, dst + (half * 128 + 64 + wave8) * 64);
}

// MODE 0: bf16 C    MODE 1: fp32 C
template <int MODE>
__global__ __launch_bounds__(512, 2) void gemm256(const bf16_t* __restrict__ A,
                                                  const bf16_t* __restrict__ Bt,
                                                  const float* __restrict__ bias,
                                                  void* __restrict__ Cout) {
  constexpr int K = 1024, N = 1024;
  __shared__ bf16_t sA0[256 * 64];
  __shared__ bf16_t sB0[256 * 64];
  __shared__ bf16_t sA1[256 * 64];
  __shared__ bf16_t sB1[256 * 64];

  const int tid = threadIdx.x;
  const int lane = tid & 63, wave = tid >> 6;
  const int lrow = lane & 15, quad = lane >> 4, swz = lrow & 7;
  const int wm = (wave >> 2) * 64;   // 0 / 64   (M offset inside each 128-half)
  const int wn = (wave & 3) * 32;    // 0..96    (N offset inside each 128-half)
  const int wave8 = wave * 8;

  // XCD-bijective decode: 8 consecutive by-bands per XCD; 4 bx blocks of a by on one XCD.
  const int id = blockIdx.x;                     // 0..255
  const int bx = (id >> 3) & 3;                  // N block
  const int by = ((id & 7) << 3) | (id >> 5);    // M block 0..63
  const int m0 = by * 256, n0 = bx * 256;

  // staging source: 64 rows x 8 colgroups per pass, swizzled col (T2, both-sides scheme)
  const int srow = tid >> 3;                          // 0..63
  const int scg = ((tid & 7) ^ (srow & 7)) * 8;       // swizzled k-group
  const bf16_t* gA = A + (size_t)(m0 + srow) * K + scg;
  const bf16_t* gB = Bt + (size_t)(n0 + srow) * K + scg;

  f32x4 acc[8][4];
#pragma unroll
  for (int i = 0; i < 8; ++i)
#pragma unroll
    for (int j = 0; j < 4; ++j) acc[i][j] = (f32x4){0.f, 0.f, 0.f, 0.f};

  // prologue: tile0 fully + tile1 h0 (order matters for FIFO vmcnt counting)
  stg(sA0, gA, 0, 0, wave8);
  stg(sB0, gB, 0, 0, wave8);
  stg(sA0, gA, 1, 0, wave8);
  stg(sB0, gB, 1, 0, wave8);
  stg(sA1, gA, 0, 64, wave8);
  stg(sB1, gB, 0, 64, wave8);
  WAITVM(8);   // A0h0,B0h0 landed; 4 half-tiles in flight
  BARRIER();

  bf16x8 af[2][4], bf0[2][2], bf1[2][2];

#pragma unroll 1
  for (int it = 0; it < 7; ++it) {   // tiles t=2it, t+1; NT=16, last pair peeled
    const int kb = it * 128;
    // P0: read A(t)h0 + B(t)h0; stage A(t+1)h1
    lda4(af, sA0, wm + lrow, quad, swz);
    ldb2(bf0, sB0, wn + lrow, quad, swz);
    stg(sA1, gA, 1, kb + 64, wave8);
    BARRIER();
    __builtin_amdgcn_s_setprio(1); mm16<0, 0>(acc, af, bf0); __builtin_amdgcn_s_setprio(0);
    WAITVM(6);
    BARRIER();
    // P1: read B(t)h1; stage B(t+1)h1
    ldb2(bf1, sB0, 128 + wn + lrow, quad, swz);
    stg(sB1, gB, 1, kb + 64, wave8);
    BARRIER();
    __builtin_amdgcn_s_setprio(1); mm16<0, 1>(acc, af, bf1); __builtin_amdgcn_s_setprio(0);
    BARRIER();
    // P2: read A(t)h1; stage A(t+2)h0
    lda4(af, sA0, 128 + wm + lrow, quad, swz);
    stg(sA0, gA, 0, kb + 128, wave8);
    BARRIER();
    __builtin_amdgcn_s_setprio(1); mm16<1, 0>(acc, af, bf0); __builtin_amdgcn_s_setprio(0);
    BARRIER();
    // P3: stage B(t+2)h0
    stg(sB0, gB, 0, kb + 128, wave8);
    BARRIER();
    __builtin_amdgcn_s_setprio(1); mm16<1, 1>(acc, af, bf1); __builtin_amdgcn_s_setprio(0);
    WAITVM(8);
    BARRIER();
    // P4: read A(t+1)h0 + B(t+1)h0; stage A(t+2)h1
    lda4(af, sA1, wm + lrow, quad, swz);
    ldb2(bf0, sB1, wn + lrow, quad, swz);
    stg(sA0, gA, 1, kb + 128, wave8);
    BARRIER();
    __builtin_amdgcn_s_setprio(1); mm16<0, 0>(acc, af, bf0); __builtin_amdgcn_s_setprio(0);
    WAITVM(6);
    BARRIER();
    // P5: read B(t+1)h1; stage B(t+2)h1
    ldb2(bf1, sB1, 128 + wn + lrow, quad, swz);
    stg(sB0, gB, 1, kb + 128, wave8);
    BARRIER();
    __builtin_amdgcn_s_setprio(1); mm16<0, 1>(acc, af, bf1); __builtin_amdgcn_s_setprio(0);
    BARRIER();
    // P6: read A(t+1)h1; stage A(t+3)h0
    lda4(af, sA1, 128 + wm + lrow, quad, swz);
    stg(sA1, gA, 0, kb + 192, wave8);
    BARRIER();
    __builtin_amdgcn_s_setprio(1); mm16<1, 0>(acc, af, bf0); __builtin_amdgcn_s_setprio(0);
    BARRIER();
    // P7: stage B(t+3)h0
    stg(sB1, gB, 0, kb + 192, wave8);
    BARRIER();
    __builtin_amdgcn_s_setprio(1); mm16<1, 1>(acc, af, bf1); __builtin_amdgcn_s_setprio(0);
    WAITVM(8);
    BARRIER();
  }

  // peeled final iteration: tiles 14 (kb=896) and 15; no t+2/t+3 stages -> tightened waits
  {
    const int kb = 896;
    // P0: stage A(15)h1
    lda4(af, sA0, wm + lrow, quad, swz);
    ldb2(bf0, sB0, wn + lrow, quad, swz);
    stg(sA1, gA, 1, kb + 64, wave8);
    BARRIER();
    __builtin_amdgcn_s_setprio(1); mm16<0, 0>(acc, af, bf0); __builtin_amdgcn_s_setprio(0);
    WAITVM(6);
    BARRIER();
    // P1: stage B(15)h1
    ldb2(bf1, sB0, 128 + wn + lrow, quad, swz);
    stg(sB1, gB, 1, kb + 64, wave8);
    BARRIER();
    __builtin_amdgcn_s_setprio(1); mm16<0, 1>(acc, af, bf1); __builtin_amdgcn_s_setprio(0);
    BARRIER();
    // P2
    lda4(af, sA0, 128 + wm + lrow, quad, swz);
    BARRIER();
    __builtin_amdgcn_s_setprio(1); mm16<1, 0>(acc, af, bf0); __builtin_amdgcn_s_setprio(0);
    BARRIER();
    // P3
    BARRIER();
    __builtin_amdgcn_s_setprio(1); mm16<1, 1>(acc, af, bf1); __builtin_amdgcn_s_setprio(0);
    WAITVM(4);
    BARRIER();
    // P4
    lda4(af, sA1, wm + lrow, quad, swz);
    ldb2(bf0, sB1, wn + lrow, quad, swz);
    BARRIER();
    __builtin_amdgcn_s_setprio(1); mm16<0, 0>(acc, af, bf0); __builtin_amdgcn_s_setprio(0);
    WAITVM(0);
    BARRIER();
    // P5
    ldb2(bf1, sB1, 128 + wn + lrow, quad, swz);
    BARRIER();
    __builtin_amdgcn_s_setprio(1); mm16<0, 1>(acc, af, bf1); __builtin_amdgcn_s_setprio(0);
    BARRIER();
    // P6
    lda4(af, sA1, 128 + wm + lrow, quad, swz);
    BARRIER();
    __builtin_amdgcn_s_setprio(1); mm16<1, 0>(acc, af, bf0); __builtin_amdgcn_s_setprio(0);
    BARRIER();
    // P7
    __builtin_amdgcn_s_setprio(1); mm16<1, 1>(acc, af, bf1); __builtin_amdgcn_s_setprio(0);
  }

  // epilogue
  float bv_[4];
#pragma unroll
  for (int nj = 0; nj < 4; ++nj)
    bv_[nj] = bias[n0 + (nj >> 1) * 128 + wn + (nj & 1) * 16 + lrow];

  if constexpr (MODE == 0) {
    bf16_t* C = (bf16_t*)Cout;
#pragma unroll
    for (int mi = 0; mi < 8; ++mi) {
      int row = m0 + (mi >> 2) * 128 + wm + (mi & 3) * 16 + quad * 4;
#pragma unroll
      for (int nj = 0; nj < 4; ++nj) {
        int col = n0 + (nj >> 1) * 128 + wn + (nj & 1) * 16 + lrow;
#pragma unroll
        for (int r = 0; r < 4; ++r)
          C[(size_t)(row + r) * N + col] = (bf16_t)(acc[mi][nj][r] + bv_[nj]);
      }
    }
  } else {
    float* C = (float*)Cout;
#pragma unroll
    for (int mi = 0; mi < 8; ++mi) {
      int row = m0 + (mi >> 2) * 128 + wm + (mi & 3) * 16 + quad * 4;
#pragma unroll
      for (int nj = 0; nj < 4; ++nj) {
        int col = n0 + (nj >> 1) * 128 + wn + (nj & 1) * 16 + lrow;
#pragma unroll
        for (int r = 0; r < 4; ++r)
          C[(size_t)(row + r) * N + col] = acc[mi][nj][r] + bv_[nj];
      }
    }
  }
}

// ---------------- kv accumulation via MFMA: per-wave partials (no atomics) ----------------
// grid: 64 bh * 8 chunks (512 n-rows each). Round-1-proven structure; each wave reduces a
// DISJOINT 32-row slice per 128-row stage, so each wave stores its OWN partial tile
// kvp[bx*4+wave][64][64] (addresses disjoint -> no races). kv_reduce sums 32 partials/bh.
#define KVCH 512
__global__ __launch_bounds__(256) void kv_accum_mfma(const bf16_t* __restrict__ kp,
                                                     const bf16_t* __restrict__ vp,
                                                     float* __restrict__ kvp) {
  __shared__ bf16_t sK[128][66];
  __shared__ bf16_t sV[128][66];
  int bx = blockIdx.x;
  int chunk = bx & 7;
  int bh = bx >> 3;
  int b = bh >> 4, h = bh & 15;
  int tid = threadIdx.x, lane = tid & 63, wave = tid >> 6;
  int lrow = lane & 15, quad = lane >> 4;

  f32x4 zero = {0.f, 0.f, 0.f, 0.f};
  f32x4 acc[4][4];
#pragma unroll
  for (int i = 0; i < 4; ++i)
#pragma unroll
    for (int j = 0; j < 4; ++j) acc[i][j] = zero;

  const int srow = tid >> 3;        // 0..31
  const int scol = (tid & 7) * 8;
  const size_t gbase0 = ((size_t)(b * SEQ + chunk * KVCH)) * DMODEL + h * 64 + scol;
  const int krow0 = wave * 32 + quad * 8;

  for (int s = 0; s < KVCH / 128; ++s) {
    bf16x8 kr[4], vr[4];
#pragma unroll
    for (int p = 0; p < 4; ++p) {
      size_t g = gbase0 + (size_t)(s * 128 + p * 32 + srow) * DMODEL;
      kr[p] = *(const bf16x8*)(kp + g);
      vr[p] = *(const bf16x8*)(vp + g);
    }
    __syncthreads();
#pragma unroll
    for (int p = 0; p < 4; ++p) {
      *(bf16x8*)&sK[p * 32 + srow][scol] = kr[p];
      *(bf16x8*)&sV[p * 32 + srow][scol] = vr[p];
    }
    __syncthreads();
    bf16x8 af[4], bfr[4];
#pragma unroll
    for (int i = 0; i < 4; ++i)
#pragma unroll
      for (int j = 0; j < 8; ++j) {
        af[i][j]  = sK[krow0 + j][i * 16 + lrow];
        bfr[i][j] = sV[krow0 + j][i * 16 + lrow];
      }
#pragma unroll
    for (int i = 0; i < 4; ++i)
#pragma unroll
      for (int j = 0; j < 4; ++j)
        acc[i][j] = __builtin_amdgcn_mfma_f32_16x16x32_bf16(af[i], bfr[j], acc[i][j], 0, 0, 0);
  }

  // per-wave partial store (wave term makes addresses disjoint across the 4 waves)
  float* dst = kvp + ((size_t)bx * 4 + wave) * 64 * 64;
#pragma unroll
  for (int i = 0; i < 4; ++i)
#pragma unroll
    for (int j = 0; j < 4; ++j)
#pragma unroll
      for (int r = 0; r < 4; ++r)
        dst[(i * 16 + quad * 4 + r) * 64 + j * 16 + lrow] = acc[i][j][r];
}

// ---------------- reduce 32 partials -> kv ----------------
// grid 256: block = (bh, quarter). thread sums one float4 across 32 partial tiles
// (8 chunks x 4 waves; index p = chunk*4+wave is contiguous at kvp[bh*32 + p]).
__global__ __launch_bounds__(256) void kv_reduce(const float* __restrict__ kvp,
                                                 float* __restrict__ kv) {
  int bh = blockIdx.x >> 2;
  int idx = (blockIdx.x & 3) * 1024 + threadIdx.x * 4;
  const float* src = kvp + (size_t)bh * 32 * 4096 + idx;
  float4 s = make_float4(0.f, 0.f, 0.f, 0.f);
#pragma unroll
  for (int c = 0; c < 32; ++c) {
    float4 v = *(const float4*)(src + (size_t)c * 4096);
    s.x += v.x; s.y += v.y; s.z += v.z; s.w += v.w;
  }
  *(float4*)(kv + (size_t)bh * 4096 + idx) = s;
}

// ---------------- attention apply with fused kv-norm AND fused q-xnorm ----------------
// q is the raw Q projection (bias added), row-major [16384][1024] bf16.
// q-norm is a per-row scalar -> computed from the A-fragments and applied post-MFMA.
__global__ __launch_bounds__(256) void attn_gemm(const bf16_t* __restrict__ q,
                                                 const float* __restrict__ kv,
                                                 const float* __restrict__ gamma,
                                                 bf16_t* __restrict__ att) {
  __shared__ float sKV[64][65];
  __shared__ float sScale[64];
  int bx = blockIdx.x;          // bh*32 + chunk
  int chunk = bx & 31, bh = bx >> 5;
  int b = bh >> 4, h = bh & 15;
  int tid = threadIdx.x, lane = tid & 63, wave = tid >> 6;
  int lrow = lane & 15, quad = lane >> 4;
  int n0 = chunk * 128 + wave * 32;
  const float g = gamma[h];

  // stage kv (4096 floats) + row-norm partials
  {
    const float* src = kv + (size_t)bh * 64 * 64 + (tid >> 2) * 64 + (tid & 3) * 16;
    float4 v0 = *(const float4*)src;
    float4 v1 = *(const float4*)(src + 4);
    float4 v2 = *(const float4*)(src + 8);
    float4 v3 = *(const float4*)(src + 12);
    float* d = &sKV[tid >> 2][(tid & 3) * 16];
    *(float4*)d = v0; *(float4*)(d + 4) = v1; *(float4*)(d + 8) = v2; *(float4*)(d + 12) = v3;
    float ss = v0.x*v0.x + v0.y*v0.y + v0.z*v0.z + v0.w*v0.w
             + v1.x*v1.x + v1.y*v1.y + v1.z*v1.z + v1.w*v1.w
             + v2.x*v2.x + v2.y*v2.y + v2.z*v2.z + v2.w*v2.w
             + v3.x*v3.x + v3.y*v3.y + v3.z*v3.z + v3.w*v3.w;
    ss += __shfl_xor(ss, 1);
    ss += __shfl_xor(ss, 2);
    if ((tid & 3) == 0) sScale[tid >> 2] = g * rsqrtf(ss);
  }
  __syncthreads();

  const bf16_t* qbase = q + (size_t)b * SEQ * DMODEL + (size_t)h * 64;

  // load q frags for both ks
  bf16x8 af[2][2];
#pragma unroll
  for (int ks = 0; ks < 2; ++ks)
#pragma unroll
    for (int i = 0; i < 2; ++i)
      af[ks][i] = *(const bf16x8*)(qbase + (size_t)(n0 + i * 16 + lrow) * DMODEL + ks * 32 + quad * 8);

  // per-row q xnorm scale: ss over full 64 k; redistribute lrow->quad*4+r lanes
  float qsc[2][4];
#pragma unroll
  for (int i = 0; i < 2; ++i) {
    float ss = 0.f;
#pragma unroll
    for (int ks = 0; ks < 2; ++ks)
#pragma unroll
      for (int e = 0; e < 8; ++e) { float v = (float)af[ks][i][e]; ss += v * v; }
    ss += __shfl_xor(ss, 16);
    ss += __shfl_xor(ss, 32);
#pragma unroll
    for (int r = 0; r < 4; ++r)
      qsc[i][r] = g * rsqrtf(__shfl(ss, quad * 4 + r));
  }

  f32x4 zero = {0.f, 0.f, 0.f, 0.f};
  f32x4 acc[2][4];
#pragma unroll
  for (int i = 0; i < 2; ++i)
#pragma unroll
    for (int j = 0; j < 4; ++j) acc[i][j] = zero;

#pragma unroll
  for (int ks = 0; ks < 2; ++ks) {
    int k0 = ks * 32 + quad * 8;
    float sc[8];
#pragma unroll
    for (int j = 0; j < 8; ++j) sc[j] = sScale[k0 + j];
    bf16x8 bfr[4];
#pragma unroll
    for (int jt = 0; jt < 4; ++jt)
#pragma unroll
      for (int j = 0; j < 8; ++j)
        bfr[jt][j] = (bf16_t)(sKV[k0 + j][jt * 16 + lrow] * sc[j]);
#pragma unroll
    for (int i = 0; i < 2; ++i)
#pragma unroll
      for (int j = 0; j < 4; ++j)
        acc[i][j] = __builtin_amdgcn_mfma_f32_16x16x32_bf16(af[ks][i], bfr[j], acc[i][j], 0, 0, 0);
  }
#pragma unroll
  for (int i = 0; i < 2; ++i)
#pragma unroll
    for (int j = 0; j < 4; ++j)
#pragma unroll
      for (int r = 0; r < 4; ++r) {
        int n = n0 + i * 16 + quad * 4 + r;
        att[((size_t)(b * SEQ + n)) * DMODEL + h * 64 + j * 16 + lrow] =
            (bf16_t)(acc[i][j][r] * qsc[i][r]);
      }
}

// ---------------- launch ----------------
extern "C" void kernel_launch(void* const* d_in, const int* in_sizes, int n_in,
                              void* d_out, int out_size, void* d_ws, size_t ws_size,
                              hipStream_t stream) {
  const float* queries = (const float*)d_in[0];
  const float* keys    = (const float*)d_in[1];
  const float* values  = (const float*)d_in[2];
  const float* Wq = (const float*)d_in[3];
  const float* bq = (const float*)d_in[4];
  const float* Wk = (const float*)d_in[5];
  const float* bk = (const float*)d_in[6];
  const float* Wv = (const float*)d_in[7];
  const float* bv = (const float*)d_in[8];
  const float* Wo = (const float*)d_in[9];
  const float* bo = (const float*)d_in[10];
  const float* gamma = (const float*)d_in[11];

  char* ws = (char*)d_ws;
  size_t off = 0;
  auto alloc = [&](size_t bytes) -> void* {
    void* p = ws + off;
    off = (off + bytes + 255) & ~(size_t)255;
    return p;
  };
  const size_t actN = (size_t)NROWS * DMODEL;
  bf16_t* wqb  = (bf16_t*)alloc((size_t)DMODEL * DMODEL * 2);
  bf16_t* wkb  = (bf16_t*)alloc((size_t)DMODEL * DMODEL * 2);
  bf16_t* wvb  = (bf16_t*)alloc((size_t)DMODEL * DMODEL * 2);
  bf16_t* wob  = (bf16_t*)alloc((size_t)DMODEL * DMODEL * 2);
  bf16_t* actb = (bf16_t*)alloc(actN * 2);   // rotating bf16 A-operand buffer
  bf16_t* bufA = (bf16_t*)alloc(actN * 2);   // kproj, later qproj
  bf16_t* bufB = (bf16_t*)alloc(actN * 2);   // vproj, later att
  float*  kv   = (float*)alloc((size_t)64 * 64 * 64 * 4);

  // kv partials (32 MB = 512 blocks x 4 waves x 4096 floats): prefer workspace if it
  // fits, else use d_out (64 MB fp32, dead until the final Wo GEMM overwrites it).
  const size_t kvp_bytes = (size_t)512 * 4 * 4096 * 4;
  float* kvp = (off + kvp_bytes <= ws_size) ? (float*)alloc(kvp_bytes) : (float*)d_out;

  int w8 = DMODEL * DMODEL / 8;
  int act8 = (int)(actN / 8);

  // weight conversions (4 jobs)
  f2b4_kernel<<<dim3(w8 / 256, 4), 256, 0, stream>>>(Wk, wkb, Wv, wvb, Wq, wqb, Wo, wob, w8);

  // K projection
  f2b_kernel<<<act8 / 256, 256, 0, stream>>>(keys, actb, act8);
  gemm256<0><<<256, 512, 0, stream>>>(actb, wkb, bk, bufA);
  // V projection
  f2b_kernel<<<act8 / 256, 256, 0, stream>>>(values, actb, act8);
  gemm256<0><<<256, 512, 0, stream>>>(actb, wvb, bv, bufB);

  // kv per-wave partials (no atomics) + reduce
  kv_accum_mfma<<<64 * 8, 256, 0, stream>>>(bufA, bufB, kvp);
  kv_reduce<<<256, 256, 0, stream>>>(kvp, kv);

  // Q projection (plain; xnorm fused into attn_gemm) -> bufA (dead kproj)
  f2b_kernel<<<act8 / 256, 256, 0, stream>>>(queries, actb, act8);
  gemm256<0><<<256, 512, 0, stream>>>(actb, wqb, bq, bufA);

  // attention apply with fused kv-norm + q-norm -> att (into bufB, dead vproj)
  attn_gemm<<<64 * 32, 256, 0, stream>>>(bufA, kv, gamma, bufB);

  // output projection (fp32 out + bias)
  gemm256<1><<<256, 512, 0, stream>>>(bufB, wob, bo, d_out);
}

// Round 8
// 422.825 us; speedup vs baseline: 1.1816x; 1.0052x over previous
//
#include <hip/hip_runtime.h>
#include <hip/hip_bf16.h>
#include <stdint.h>

typedef __bf16 bf16_t;
typedef __bf16 bf16x8 __attribute__((ext_vector_type(8)));
typedef float f32x4 __attribute__((ext_vector_type(4)));

#define SEQ    4096
#define NROWS  16384   // B * N
#define DMODEL 1024
#define NH     16

// async 16B global->LDS DMA. LDS dest is wave-uniform base + lane*16 (m104).
__device__ __forceinline__ void async_cp16(const bf16_t* g, bf16_t* l) {
  __builtin_amdgcn_global_load_lds((const __attribute__((address_space(1))) void*)g,
                                   (__attribute__((address_space(3))) void*)l,
                                   16, 0, 0);
}

#define BARRIER() asm volatile("s_barrier" ::: "memory")
#define WAITVM(N) asm volatile("s_waitcnt vmcnt(" #N ")" ::: "memory")

// ---------------- fp32 -> bf16 convert (8 elems/thread) ----------------
__device__ __forceinline__ void f2b_one(const float* __restrict__ x, bf16_t* __restrict__ y, int i) {
  const float4* xp = (const float4*)x + (size_t)i * 2;
  float4 a = xp[0], b = xp[1];
  bf16x8 o;
  o[0] = (bf16_t)a.x; o[1] = (bf16_t)a.y; o[2] = (bf16_t)a.z; o[3] = (bf16_t)a.w;
  o[4] = (bf16_t)b.x; o[5] = (bf16_t)b.y; o[6] = (bf16_t)b.z; o[7] = (bf16_t)b.w;
  *((bf16x8*)y + i) = o;
}

__global__ __launch_bounds__(256) void f2b_kernel(const float* __restrict__ x,
                                                  bf16_t* __restrict__ y, int n8) {
  int i = blockIdx.x * 256 + threadIdx.x;
  if (i >= n8) return;
  f2b_one(x, y, i);
}

// keys+values in one dispatch (blockIdx.y selects tensor)
__global__ __launch_bounds__(256) void f2b2_kernel(const float* __restrict__ x0, bf16_t* __restrict__ y0,
                                                   const float* __restrict__ x1, bf16_t* __restrict__ y1,
                                                   int n8) {
  int i = blockIdx.x * 256 + threadIdx.x;
  if (i >= n8) return;
  const float* x = blockIdx.y ? x1 : x0;
  bf16_t* y = blockIdx.y ? y1 : y0;
  f2b_one(x, y, i);
}

// 4 weight conversions in one dispatch (blockIdx.y selects job)
__global__ __launch_bounds__(256) void f2b4_kernel(const float* __restrict__ x0, bf16_t* __restrict__ y0,
                                                   const float* __restrict__ x1, bf16_t* __restrict__ y1,
                                                   const float* __restrict__ x2, bf16_t* __restrict__ y2,
                                                   const float* __restrict__ x3, bf16_t* __restrict__ y3,
                                                   int n8) {
  int i = blockIdx.x * 256 + threadIdx.x;
  if (i >= n8) return;
  const float* x = (blockIdx.y == 0) ? x0 : (blockIdx.y == 1) ? x1 : (blockIdx.y == 2) ? x2 : x3;
  bf16_t* y = (blockIdx.y == 0) ? y0 : (blockIdx.y == 1) ? y1 : (blockIdx.y == 2) ? y2 : y3;
  f2b_one(x, y, i);
}

// ---------------- 256x256 8-phase GEMM (T2+T3+T4+T5) ----------------
// C[m,n] = sum_k A[m,k]*Bt[n,k] + bias[n].  M=16384, N=1024, K=1024 fixed.
// 512 threads = 8 waves (2M x 4N), per-wave out 128x64 (acc[8][4]).
// LDS: 2 K-tile buffers x (A[256][64] + B[256][64]) bf16 = 128 KiB.
// Raw s_barrier + counted vmcnt (8/6 per wait point); never drains to 0 in main loop.

template <int QM, int QN>
__device__ __forceinline__ void mm16(f32x4 (&acc)[8][4], const bf16x8 (&af)[2][4],
                                     const bf16x8 (&bf)[2][2]) {
#pragma unroll
  for (int ks = 0; ks < 2; ++ks)
#pragma unroll
    for (int i = 0; i < 4; ++i)
#pragma unroll
      for (int j = 0; j < 2; ++j)
        acc[QM * 4 + i][QN * 2 + j] = __builtin_amdgcn_mfma_f32_16x16x32_bf16(
            af[ks][i], bf[ks][j], acc[QM * 4 + i][QN * 2 + j], 0, 0, 0);
}

__device__ __forceinline__ void lda4(bf16x8 (&af)[2][4], const bf16_t* buf, int row0,
                                     int quad, int swz) {
#pragma unroll
  for (int ks = 0; ks < 2; ++ks)
#pragma unroll
    for (int i = 0; i < 4; ++i)
      af[ks][i] = *(const bf16x8*)(buf + (row0 + i * 16) * 64 + (((ks * 4 + quad) ^ swz) * 8));
}

__device__ __forceinline__ void ldb2(bf16x8 (&bf)[2][2], const bf16_t* buf, int row0,
                                     int quad, int swz) {
#pragma unroll
  for (int ks = 0; ks < 2; ++ks)
#pragma unroll
    for (int j = 0; j < 2; ++j)
      bf[ks][j] = *(const bf16x8*)(buf + (row0 + j * 16) * 64 + (((ks * 4 + quad) ^ swz) * 8));
}

// gsrc already includes per-thread (row, swizzled col) offset; dest is wave-uniform.
__device__ __forceinline__ void stg(bf16_t* dst, const bf16_t* gsrc, int half, int kb,
                                    int wave8) {
  async_cp16(gsrc + (size_t)(half * 128) * 1024 + kb, dst + (half * 128 + wave8) * 64);
  async_cp16(gsrc + (size_t)(half * 128 + 64) * 1024 + kb, dst + (half * 128 + 64 + wave8) * 64);
}

// MODE 0: bf16 C    MODE 1: fp32 C
template <int MODE>
__device__ __forceinline__ void gemm_body(const bf16_t* __restrict__ A,
                                          const bf16_t* __restrict__ Bt,
                                          const float* __restrict__ bias,
                                          void* __restrict__ Cout,
                                          int id, int tid) {
  constexpr int K = 1024, N = 1024;
  __shared__ bf16_t sA0[256 * 64];
  __shared__ bf16_t sB0[256 * 64];
  __shared__ bf16_t sA1[256 * 64];
  __shared__ bf16_t sB1[256 * 64];

  const int lane = tid & 63, wave = tid >> 6;
  const int lrow = lane & 15, quad = lane >> 4, swz = lrow & 7;
  const int wm = (wave >> 2) * 64;   // 0 / 64   (M offset inside each 128-half)
  const int wn = (wave & 3) * 32;    // 0..96    (N offset inside each 128-half)
  const int wave8 = wave * 8;

  // XCD-bijective decode: 8 consecutive by-bands per XCD; 4 bx blocks of a by on one XCD.
  const int bx = (id >> 3) & 3;                  // N block
  const int by = ((id & 7) << 3) | (id >> 5);    // M block 0..63
  const int m0 = by * 256, n0 = bx * 256;

  // staging source: 64 rows x 8 colgroups per pass, swizzled col (T2, both-sides scheme)
  const int srow = tid >> 3;                          // 0..63
  const int scg = ((tid & 7) ^ (srow & 7)) * 8;       // swizzled k-group
  const bf16_t* gA = A + (size_t)(m0 + srow) * K + scg;
  const bf16_t* gB = Bt + (size_t)(n0 + srow) * K + scg;

  f32x4 acc[8][4];
#pragma unroll
  for (int i = 0; i < 8; ++i)
#pragma unroll
    for (int j = 0; j < 4; ++j) acc[i][j] = (f32x4){0.f, 0.f, 0.f, 0.f};

  // prologue: tile0 fully + tile1 h0 (order matters for FIFO vmcnt counting)
  stg(sA0, gA, 0, 0, wave8);
  stg(sB0, gB, 0, 0, wave8);
  stg(sA0, gA, 1, 0, wave8);
  stg(sB0, gB, 1, 0, wave8);
  stg(sA1, gA, 0, 64, wave8);
  stg(sB1, gB, 0, 64, wave8);
  WAITVM(8);   // A0h0,B0h0 landed; 4 half-tiles in flight
  BARRIER();

  bf16x8 af[2][4], bf0[2][2], bf1[2][2];

#pragma unroll 1
  for (int it = 0; it < 7; ++it) {   // tiles t=2it, t+1; NT=16, last pair peeled
    const int kb = it * 128;
    // P0: read A(t)h0 + B(t)h0; stage A(t+1)h1
    lda4(af, sA0, wm + lrow, quad, swz);
    ldb2(bf0, sB0, wn + lrow, quad, swz);
    stg(sA1, gA, 1, kb + 64, wave8);
    BARRIER();
    __builtin_amdgcn_s_setprio(1); mm16<0, 0>(acc, af, bf0); __builtin_amdgcn_s_setprio(0);
    WAITVM(6);
    BARRIER();
    // P1: read B(t)h1; stage B(t+1)h1
    ldb2(bf1, sB0, 128 + wn + lrow, quad, swz);
    stg(sB1, gB, 1, kb + 64, wave8);
    BARRIER();
    __builtin_amdgcn_s_setprio(1); mm16<0, 1>(acc, af, bf1); __builtin_amdgcn_s_setprio(0);
    BARRIER();
    // P2: read A(t)h1; stage A(t+2)h0
    lda4(af, sA0, 128 + wm + lrow, quad, swz);
    stg(sA0, gA, 0, kb + 128, wave8);
    BARRIER();
    __builtin_amdgcn_s_setprio(1); mm16<1, 0>(acc, af, bf0); __builtin_amdgcn_s_setprio(0);
    BARRIER();
    // P3: stage B(t+2)h0
    stg(sB0, gB, 0, kb + 128, wave8);
    BARRIER();
    __builtin_amdgcn_s_setprio(1); mm16<1, 1>(acc, af, bf1); __builtin_amdgcn_s_setprio(0);
    WAITVM(8);
    BARRIER();
    // P4: read A(t+1)h0 + B(t+1)h0; stage A(t+2)h1
    lda4(af, sA1, wm + lrow, quad, swz);
    ldb2(bf0, sB1, wn + lrow, quad, swz);
    stg(sA0, gA, 1, kb + 128, wave8);
    BARRIER();
    __builtin_amdgcn_s_setprio(1); mm16<0, 0>(acc, af, bf0); __builtin_amdgcn_s_setprio(0);
    WAITVM(6);
    BARRIER();
    // P5: read B(t+1)h1; stage B(t+2)h1
    ldb2(bf1, sB1, 128 + wn + lrow, quad, swz);
    stg(sB0, gB, 1, kb + 128, wave8);
    BARRIER();
    __builtin_amdgcn_s_setprio(1); mm16<0, 1>(acc, af, bf1); __builtin_amdgcn_s_setprio(0);
    BARRIER();
    // P6: read A(t+1)h1; stage A(t+3)h0
    lda4(af, sA1, 128 + wm + lrow, quad, swz);
    stg(sA1, gA, 0, kb + 192, wave8);
    BARRIER();
    __builtin_amdgcn_s_setprio(1); mm16<1, 0>(acc, af, bf0); __builtin_amdgcn_s_setprio(0);
    BARRIER();
    // P7: stage B(t+3)h0
    stg(sB1, gB, 0, kb + 192, wave8);
    BARRIER();
    __builtin_amdgcn_s_setprio(1); mm16<1, 1>(acc, af, bf1); __builtin_amdgcn_s_setprio(0);
    WAITVM(8);
    BARRIER();
  }

  // peeled final iteration: tiles 14 (kb=896) and 15; no t+2/t+3 stages -> tightened waits
  {
    const int kb = 896;
    // P0: stage A(15)h1
    lda4(af, sA0, wm + lrow, quad, swz);
    ldb2(bf0, sB0, wn + lrow, quad, swz);
    stg(sA1, gA, 1, kb + 64, wave8);
    BARRIER();
    __builtin_amdgcn_s_setprio(1); mm16<0, 0>(acc, af, bf0); __builtin_amdgcn_s_setprio(0);
    WAITVM(6);
    BARRIER();
    // P1: stage B(15)h1
    ldb2(bf1, sB0, 128 + wn + lrow, quad, swz);
    stg(sB1, gB, 1, kb + 64, wave8);
    BARRIER();
    __builtin_amdgcn_s_setprio(1); mm16<0, 1>(acc, af, bf1); __builtin_amdgcn_s_setprio(0);
    BARRIER();
    // P2
    lda4(af, sA0, 128 + wm + lrow, quad, swz);
    BARRIER();
    __builtin_amdgcn_s_setprio(1); mm16<1, 0>(acc, af, bf0); __builtin_amdgcn_s_setprio(0);
    BARRIER();
    // P3
    BARRIER();
    __builtin_amdgcn_s_setprio(1); mm16<1, 1>(acc, af, bf1); __builtin_amdgcn_s_setprio(0);
    WAITVM(4);
    BARRIER();
    // P4
    lda4(af, sA1, wm + lrow, quad, swz);
    ldb2(bf0, sB1, wn + lrow, quad, swz);
    BARRIER();
    __builtin_amdgcn_s_setprio(1); mm16<0, 0>(acc, af, bf0); __builtin_amdgcn_s_setprio(0);
    WAITVM(0);
    BARRIER();
    // P5
    ldb2(bf1, sB1, 128 + wn + lrow, quad, swz);
    BARRIER();
    __builtin_amdgcn_s_setprio(1); mm16<0, 1>(acc, af, bf1); __builtin_amdgcn_s_setprio(0);
    BARRIER();
    // P6
    lda4(af, sA1, 128 + wm + lrow, quad, swz);
    BARRIER();
    __builtin_amdgcn_s_setprio(1); mm16<1, 0>(acc, af, bf0); __builtin_amdgcn_s_setprio(0);
    BARRIER();
    // P7
    __builtin_amdgcn_s_setprio(1); mm16<1, 1>(acc, af, bf1); __builtin_amdgcn_s_setprio(0);
  }

  // epilogue
  float bv_[4];
#pragma unroll
  for (int nj = 0; nj < 4; ++nj)
    bv_[nj] = bias[n0 + (nj >> 1) * 128 + wn + (nj & 1) * 16 + lrow];

  if constexpr (MODE == 0) {
    bf16_t* C = (bf16_t*)Cout;
#pragma unroll
    for (int mi = 0; mi < 8; ++mi) {
      int row = m0 + (mi >> 2) * 128 + wm + (mi & 3) * 16 + quad * 4;
#pragma unroll
      for (int nj = 0; nj < 4; ++nj) {
        int col = n0 + (nj >> 1) * 128 + wn + (nj & 1) * 16 + lrow;
#pragma unroll
        for (int r = 0; r < 4; ++r)
          C[(size_t)(row + r) * N + col] = (bf16_t)(acc[mi][nj][r] + bv_[nj]);
      }
    }
  } else {
    float* C = (float*)Cout;
#pragma unroll
    for (int mi = 0; mi < 8; ++mi) {
      int row = m0 + (mi >> 2) * 128 + wm + (mi & 3) * 16 + quad * 4;
#pragma unroll
      for (int nj = 0; nj < 4; ++nj) {
        int col = n0 + (nj >> 1) * 128 + wn + (nj & 1) * 16 + lrow;
#pragma unroll
        for (int r = 0; r < 4; ++r)
          C[(size_t)(row + r) * N + col] = acc[mi][nj][r] + bv_[nj];
      }
    }
  }
}

template <int MODE>
__global__ __launch_bounds__(512, 2) void gemm256(const bf16_t* __restrict__ A,
                                                  const bf16_t* __restrict__ Bt,
                                                  const float* __restrict__ bias,
                                                  void* __restrict__ Cout) {
  gemm_body<MODE>(A, Bt, bias, Cout, blockIdx.x, threadIdx.x);
}

// two independent MODE-0 GEMMs in one 512-block dispatch (blocks 0-255 = job 0).
__global__ __launch_bounds__(512, 2) void gemm_pair(const bf16_t* __restrict__ A0,
                                                    const bf16_t* __restrict__ Bt0,
                                                    const float* __restrict__ b0,
                                                    void* __restrict__ C0,
                                                    const bf16_t* __restrict__ A1,
                                                    const bf16_t* __restrict__ Bt1,
                                                    const float* __restrict__ b1,
                                                    void* __restrict__ C1) {
  const int sel = blockIdx.x >> 8;
  const int id = blockIdx.x & 255;
  const bf16_t* A = sel ? A1 : A0;
  const bf16_t* Bt = sel ? Bt1 : Bt0;
  const float* bias = sel ? b1 : b0;
  void* C = sel ? C1 : C0;
  gemm_body<0>(A, Bt, bias, C, id, threadIdx.x);
}

// ---------------- kv accumulation via MFMA: per-wave partials (no atomics) ----------------
// grid: 64 bh * 8 chunks (512 n-rows each). Each wave reduces a DISJOINT 32-row slice per
// 128-row stage -> per-wave partial tile kvp[bx*4+wave][64][64]. kv_reduce sums 32/bh.
#define KVCH 512
__global__ __launch_bounds__(256) void kv_accum_mfma(const bf16_t* __restrict__ kp,
                                                     const bf16_t* __restrict__ vp,
                                                     float* __restrict__ kvp) {
  __shared__ bf16_t sK[128][66];
  __shared__ bf16_t sV[128][66];
  int bx = blockIdx.x;
  int chunk = bx & 7;
  int bh = bx >> 3;
  int b = bh >> 4, h = bh & 15;
  int tid = threadIdx.x, lane = tid & 63, wave = tid >> 6;
  int lrow = lane & 15, quad = lane >> 4;

  f32x4 zero = {0.f, 0.f, 0.f, 0.f};
  f32x4 acc[4][4];
#pragma unroll
  for (int i = 0; i < 4; ++i)
#pragma unroll
    for (int j = 0; j < 4; ++j) acc[i][j] = zero;

  const int srow = tid >> 3;        // 0..31
  const int scol = (tid & 7) * 8;
  const size_t gbase0 = ((size_t)(b * SEQ + chunk * KVCH)) * DMODEL + h * 64 + scol;
  const int krow0 = wave * 32 + quad * 8;

  for (int s = 0; s < KVCH / 128; ++s) {
    bf16x8 kr[4], vr[4];
#pragma unroll
    for (int p = 0; p < 4; ++p) {
      size_t g = gbase0 + (size_t)(s * 128 + p * 32 + srow) * DMODEL;
      kr[p] = *(const bf16x8*)(kp + g);
      vr[p] = *(const bf16x8*)(vp + g);
    }
    __syncthreads();
#pragma unroll
    for (int p = 0; p < 4; ++p) {
      *(bf16x8*)&sK[p * 32 + srow][scol] = kr[p];
      *(bf16x8*)&sV[p * 32 + srow][scol] = vr[p];
    }
    __syncthreads();
    bf16x8 af[4], bfr[4];
#pragma unroll
    for (int i = 0; i < 4; ++i)
#pragma unroll
      for (int j = 0; j < 8; ++j) {
        af[i][j]  = sK[krow0 + j][i * 16 + lrow];
        bfr[i][j] = sV[krow0 + j][i * 16 + lrow];
      }
#pragma unroll
    for (int i = 0; i < 4; ++i)
#pragma unroll
      for (int j = 0; j < 4; ++j)
        acc[i][j] = __builtin_amdgcn_mfma_f32_16x16x32_bf16(af[i], bfr[j], acc[i][j], 0, 0, 0);
  }

  // per-wave partial store (wave term makes addresses disjoint across the 4 waves)
  float* dst = kvp + ((size_t)bx * 4 + wave) * 64 * 64;
#pragma unroll
  for (int i = 0; i < 4; ++i)
#pragma unroll
    for (int j = 0; j < 4; ++j)
#pragma unroll
      for (int r = 0; r < 4; ++r)
        dst[(i * 16 + quad * 4 + r) * 64 + j * 16 + lrow] = acc[i][j][r];
}

// ---------------- reduce 32 partials -> kv ----------------
__global__ __launch_bounds__(256) void kv_reduce(const float* __restrict__ kvp,
                                                 float* __restrict__ kv) {
  int bh = blockIdx.x >> 2;
  int idx = (blockIdx.x & 3) * 1024 + threadIdx.x * 4;
  const float* src = kvp + (size_t)bh * 32 * 4096 + idx;
  float4 s = make_float4(0.f, 0.f, 0.f, 0.f);
#pragma unroll
  for (int c = 0; c < 32; ++c) {
    float4 v = *(const float4*)(src + (size_t)c * 4096);
    s.x += v.x; s.y += v.y; s.z += v.z; s.w += v.w;
  }
  *(float4*)(kv + (size_t)bh * 4096 + idx) = s;
}

// ---------------- attention apply with fused kv-norm AND fused q-xnorm ----------------
__global__ __launch_bounds__(256) void attn_gemm(const bf16_t* __restrict__ q,
                                                 const float* __restrict__ kv,
                                                 const float* __restrict__ gamma,
                                                 bf16_t* __restrict__ att) {
  __shared__ float sKV[64][65];
  __shared__ float sScale[64];
  int bx = blockIdx.x;          // bh*32 + chunk
  int chunk = bx & 31, bh = bx >> 5;
  int b = bh >> 4, h = bh & 15;
  int tid = threadIdx.x, lane = tid & 63, wave = tid >> 6;
  int lrow = lane & 15, quad = lane >> 4;
  int n0 = chunk * 128 + wave * 32;
  const float g = gamma[h];

  // stage kv (4096 floats) + row-norm partials
  {
    const float* src = kv + (size_t)bh * 64 * 64 + (tid >> 2) * 64 + (tid & 3) * 16;
    float4 v0 = *(const float4*)src;
    float4 v1 = *(const float4*)(src + 4);
    float4 v2 = *(const float4*)(src + 8);
    float4 v3 = *(const float4*)(src + 12);
    float* d = &sKV[tid >> 2][(tid & 3) * 16];
    *(float4*)d = v0; *(float4*)(d + 4) = v1; *(float4*)(d + 8) = v2; *(float4*)(d + 12) = v3;
    float ss = v0.x*v0.x + v0.y*v0.y + v0.z*v0.z + v0.w*v0.w
             + v1.x*v1.x + v1.y*v1.y + v1.z*v1.z + v1.w*v1.w
             + v2.x*v2.x + v2.y*v2.y + v2.z*v2.z + v2.w*v2.w
             + v3.x*v3.x + v3.y*v3.y + v3.z*v3.z + v3.w*v3.w;
    ss += __shfl_xor(ss, 1);
    ss += __shfl_xor(ss, 2);
    if ((tid & 3) == 0) sScale[tid >> 2] = g * rsqrtf(ss);
  }
  __syncthreads();

  const bf16_t* qbase = q + (size_t)b * SEQ * DMODEL + (size_t)h * 64;

  // load q frags for both ks
  bf16x8 af[2][2];
#pragma unroll
  for (int ks = 0; ks < 2; ++ks)
#pragma unroll
    for (int i = 0; i < 2; ++i)
      af[ks][i] = *(const bf16x8*)(qbase + (size_t)(n0 + i * 16 + lrow) * DMODEL + ks * 32 + quad * 8);

  // per-row q xnorm scale: ss over full 64 k; redistribute lrow->quad*4+r lanes
  float qsc[2][4];
#pragma unroll
  for (int i = 0; i < 2; ++i) {
    float ss = 0.f;
#pragma unroll
    for (int ks = 0; ks < 2; ++ks)
#pragma unroll
      for (int e = 0; e < 8; ++e) { float v = (float)af[ks][i][e]; ss += v * v; }
    ss += __shfl_xor(ss, 16);
    ss += __shfl_xor(ss, 32);
#pragma unroll
    for (int r = 0; r < 4; ++r)
      qsc[i][r] = g * rsqrtf(__shfl(ss, quad * 4 + r));
  }

  f32x4 zero = {0.f, 0.f, 0.f, 0.f};
  f32x4 acc[2][4];
#pragma unroll
  for (int i = 0; i < 2; ++i)
#pragma unroll
    for (int j = 0; j < 4; ++j) acc[i][j] = zero;

#pragma unroll
  for (int ks = 0; ks < 2; ++ks) {
    int k0 = ks * 32 + quad * 8;
    float sc[8];
#pragma unroll
    for (int j = 0; j < 8; ++j) sc[j] = sScale[k0 + j];
    bf16x8 bfr[4];
#pragma unroll
    for (int jt = 0; jt < 4; ++jt)
#pragma unroll
      for (int j = 0; j < 8; ++j)
        bfr[jt][j] = (bf16_t)(sKV[k0 + j][jt * 16 + lrow] * sc[j]);
#pragma unroll
    for (int i = 0; i < 2; ++i)
#pragma unroll
      for (int j = 0; j < 4; ++j)
        acc[i][j] = __builtin_amdgcn_mfma_f32_16x16x32_bf16(af[ks][i], bfr[j], acc[i][j], 0, 0, 0);
  }
#pragma unroll
  for (int i = 0; i < 2; ++i)
#pragma unroll
    for (int j = 0; j < 4; ++j)
#pragma unroll
      for (int r = 0; r < 4; ++r) {
        int n = n0 + i * 16 + quad * 4 + r;
        att[((size_t)(b * SEQ + n)) * DMODEL + h * 64 + j * 16 + lrow] =
            (bf16_t)(acc[i][j][r] * qsc[i][r]);
      }
}

// ---------------- launch ----------------
extern "C" void kernel_launch(void* const* d_in, const int* in_sizes, int n_in,
                              void* d_out, int out_size, void* d_ws, size_t ws_size,
                              hipStream_t stream) {
  const float* queries = (const float*)d_in[0];
  const float* keys    = (const float*)d_in[1];
  const float* values  = (const float*)d_in[2];
  const float* Wq = (const float*)d_in[3];
  const float* bq = (const float*)d_in[4];
  const float* Wk = (const float*)d_in[5];
  const float* bk = (const float*)d_in[6];
  const float* Wv = (const float*)d_in[7];
  const float* bv = (const float*)d_in[8];
  const float* Wo = (const float*)d_in[9];
  const float* bo = (const float*)d_in[10];
  const float* gamma = (const float*)d_in[11];

  char* ws = (char*)d_ws;
  size_t off = 0;
  auto alloc = [&](size_t bytes) -> void* {
    void* p = ws + off;
    off = (off + bytes + 255) & ~(size_t)255;
    return p;
  };
  const size_t actN = (size_t)NROWS * DMODEL;
  bf16_t* wqb = (bf16_t*)alloc((size_t)DMODEL * DMODEL * 2);
  bf16_t* wkb = (bf16_t*)alloc((size_t)DMODEL * DMODEL * 2);
  bf16_t* wvb = (bf16_t*)alloc((size_t)DMODEL * DMODEL * 2);
  bf16_t* wob = (bf16_t*)alloc((size_t)DMODEL * DMODEL * 2);
  bf16_t* kb  = (bf16_t*)alloc(actN * 2);   // keys bf16, later queries bf16
  bf16_t* vb  = (bf16_t*)alloc(actN * 2);   // values bf16
  bf16_t* pK  = (bf16_t*)alloc(actN * 2);   // kproj, later qproj
  bf16_t* pV  = (bf16_t*)alloc(actN * 2);   // vproj, later att
  float*  kv  = (float*)alloc((size_t)64 * 64 * 64 * 4);

  // kv partials (32 MB): prefer workspace, else d_out (dead until final Wo GEMM).
  const size_t kvp_bytes = (size_t)512 * 4 * 4096 * 4;
  float* kvp = (off + kvp_bytes <= ws_size) ? (float*)alloc(kvp_bytes) : (float*)d_out;

  int w8 = DMODEL * DMODEL / 8;
  int act8 = (int)(actN / 8);

  // weight conversions (4 jobs, one dispatch)
  f2b4_kernel<<<dim3(w8 / 256, 4), 256, 0, stream>>>(Wk, wkb, Wv, wvb, Wq, wqb, Wo, wob, w8);

  // keys + values conversion (one dispatch)
  f2b2_kernel<<<dim3(act8 / 256, 2), 256, 0, stream>>>(keys, kb, values, vb, act8);

  // K-proj + V-proj fused into one 512-block dispatch
  gemm_pair<<<512, 512, 0, stream>>>(kb, wkb, bk, pK, vb, wvb, bv, pV);

  // queries conversion into kb (keys bf16 now dead)
  f2b_kernel<<<act8 / 256, 256, 0, stream>>>(queries, kb, act8);

  // kv per-wave partials (no atomics) + reduce
  kv_accum_mfma<<<64 * 8, 256, 0, stream>>>(pK, pV, kvp);
  kv_reduce<<<256, 256, 0, stream>>>(kvp, kv);

  // Q projection (xnorm fused into attn_gemm) -> pK (kproj dead after kv_accum)
  gemm256<0><<<256, 512, 0, stream>>>(kb, wqb, bq, pK);

  // attention apply with fused kv-norm + q-norm -> pV (vproj dead)
  attn_gemm<<<64 * 32, 256, 0, stream>>>(pK, kv, gamma, pV);

  // output projection (fp32 out + bias)
  gemm256<1><<<256, 512, 0, stream>>>(pV, wob, bo, d_out);
}